// Round 1
// baseline (356.569 us; speedup 1.0000x reference)
//
#include <hip/hip_runtime.h>
#include <math.h>

#define BB 16
#define NN 2048
#define FF 64
#define SS 4
#define PP 22
#define OO 42
#define FPDIM (FF + 2*PP)   // 108

// ---------------- Kernel 1: coords = x@W_s + b_s ; feats = x@W_f + b_f ----------------
__global__ __launch_bounds__(256) void precompute_kernel(
    const float* __restrict__ x, const float* __restrict__ Ws, const float* __restrict__ bs,
    const float* __restrict__ Wf, const float* __restrict__ bf,
    float* __restrict__ coords, float* __restrict__ feats)
{
    int row = blockIdx.x * 256 + threadIdx.x;   // 0 .. B*N-1
    if (row >= BB * NN) return;

    const float4* x4 = (const float4*)(x + (size_t)row * FF);
    float c0 = bs[0], c1 = bs[1], c2 = bs[2], c3 = bs[3];
    float f[PP];
    #pragma unroll
    for (int c = 0; c < PP; c++) f[c] = bf[c];

    #pragma unroll
    for (int k4 = 0; k4 < FF / 4; k4++) {
        float4 xv = x4[k4];
        float xs[4] = {xv.x, xv.y, xv.z, xv.w};
        #pragma unroll
        for (int r = 0; r < 4; r++) {
            int k = k4 * 4 + r;
            float xk = xs[r];
            // W loads are wave-uniform (loop-counter-indexed) -> scalar loads
            c0 = fmaf(xk, Ws[k * SS + 0], c0);
            c1 = fmaf(xk, Ws[k * SS + 1], c1);
            c2 = fmaf(xk, Ws[k * SS + 2], c2);
            c3 = fmaf(xk, Ws[k * SS + 3], c3);
            #pragma unroll
            for (int c = 0; c < PP; c++) f[c] = fmaf(xk, Wf[k * PP + c], f[c]);
        }
    }
    float4* cp = (float4*)(coords + (size_t)row * SS);
    *cp = make_float4(c0, c1, c2, c3);
    float* fo = feats + (size_t)row * PP;
    #pragma unroll
    for (int c = 0; c < PP; c++) fo[c] = f[c];
}

// ---------------- Kernel 2: block per query: d2, exact top-K select, aggregate, output ----------------
__global__ __launch_bounds__(256) void gravnet_kernel(
    const float* __restrict__ x, const float* __restrict__ coords, const float* __restrict__ feats,
    const float* __restrict__ Wo, const float* __restrict__ bo,
    const int* __restrict__ nnbr, float* __restrict__ out)
{
    const int tid = threadIdx.x;
    const int bid = blockIdx.x;
    const int b = bid >> 11;       // / 2048
    const int i = bid & (NN - 1);

    int K = *nnbr;                 // 40 expected
    if (K < 2) K = 2;
    if (K > 64) K = 64;

    __shared__ float d2s[NN];                 // 8 KB
    __shared__ unsigned int hist[256];        // 1 KB
    __shared__ unsigned int sh_prefix;
    __shared__ int sh_rank;
    __shared__ int selcount, eqcount;
    __shared__ int   isel[64];
    __shared__ float wsel[64];
    __shared__ int   eqlist[64];
    __shared__ float redmax[PP * 8];
    __shared__ float redsum[PP * 8];
    __shared__ float urow[FPDIM];

    const float4* cb = (const float4*)(coords + (size_t)b * NN * SS);
    float4 q = cb[i];              // block-uniform -> scalar load

    // ---- distances (strided: lane j = r*256+tid, coalesced, conflict-free d2s store) ----
    #pragma unroll
    for (int r = 0; r < NN / 256; r++) {
        int j = r * 256 + tid;
        float4 cj = cb[j];
        float d0 = q.x - cj.x, d1 = q.y - cj.y, d2v = q.z - cj.z, d3 = q.w - cj.w;
        d2s[j] = d0 * d0 + d1 * d1 + d2v * d2v + d3 * d3;
    }
    if (tid == 0) { selcount = 0; eqcount = 0; }
    __syncthreads();

    // ---- exact K-th smallest via 4x8-bit radix select on float bits (all >= 0) ----
    unsigned int prefix = 0;
    int rank = K;
    for (int p = 3; p >= 0; p--) {
        hist[tid] = 0;
        __syncthreads();
        const int shift = p * 8;
        #pragma unroll
        for (int r = 0; r < NN / 256; r++) {
            int j = r * 256 + tid;
            unsigned int v = __float_as_uint(d2s[j]);
            bool match = (p == 3) || ((v >> (shift + 8)) == (prefix >> (shift + 8)));
            if (match) atomicAdd(&hist[(v >> shift) & 255u], 1u);
        }
        __syncthreads();
        if (tid < 64) {
            int lane = tid;
            unsigned int h0 = hist[lane * 4 + 0], h1 = hist[lane * 4 + 1];
            unsigned int h2 = hist[lane * 4 + 2], h3 = hist[lane * 4 + 3];
            unsigned int tot = h0 + h1 + h2 + h3;
            unsigned int sc = tot;                   // inclusive scan over 64 lanes
            #pragma unroll
            for (int off = 1; off < 64; off <<= 1) {
                unsigned int t = __shfl_up(sc, off, 64);
                if (lane >= off) sc += t;
            }
            unsigned int excl = sc - tot;
            if ((int)excl < rank && rank <= (int)sc) {    // exactly one lane
                unsigned int ca = excl + h0, cb2 = ca + h1, cc = cb2 + h2;
                int d; unsigned int cumb;
                if      (rank <= (int)ca)  { d = lane * 4 + 0; cumb = excl; }
                else if (rank <= (int)cb2) { d = lane * 4 + 1; cumb = ca;   }
                else if (rank <= (int)cc)  { d = lane * 4 + 2; cumb = cb2;  }
                else                       { d = lane * 4 + 3; cumb = cc;   }
                sh_prefix = prefix | ((unsigned int)d << shift);
                sh_rank = rank - (int)cumb;
            }
        }
        __syncthreads();
        prefix = sh_prefix;
        rank = sh_rank;
    }
    const unsigned int tau = prefix;   // exact bits of K-th smallest d2
    const int need_eq = rank;          // how many values == tau belong to top-K

    // ---- build neighbor list: all v < tau (excluding self) + need_eq smallest-index equals ----
    __syncthreads();
    #pragma unroll
    for (int r = 0; r < NN / 256; r++) {
        int j = r * 256 + tid;
        unsigned int v = __float_as_uint(d2s[j]);
        if (v < tau) {
            if (j != i) {
                int m = atomicAdd(&selcount, 1);
                if (m < 64) { isel[m] = j; wsel[m] = expf(-d2s[j]); }
            }
        } else if (v == tau) {
            int e = atomicAdd(&eqcount, 1);
            if (e < 64) eqlist[e] = j;
        }
    }
    __syncthreads();
    if (tid == 0) {
        int e = eqcount; if (e > 64) e = 64;
        float w = expf(-__uint_as_float(tau));
        if (e <= need_eq) {
            for (int t = 0; t < e; t++) {
                int m = selcount++; if (m < 64) { isel[m] = eqlist[t]; wsel[m] = w; }
            }
        } else {
            for (int t = 0; t < need_eq; t++) {       // smallest indices among equals
                int best = -1, bj = 0x7fffffff;
                for (int u = 0; u < e; u++) { int j = eqlist[u]; if (j >= 0 && j < bj) { bj = j; best = u; } }
                eqlist[best] = -1;
                int m = selcount++; if (m < 64) { isel[m] = bj; wsel[m] = w; }
            }
        }
    }
    __syncthreads();
    int nsel = selcount; if (nsel > 64) nsel = 64;    // expect K-1 = 39

    // ---- weighted max / mean over neighbors, 8 partials per channel ----
    if (tid < PP * 8) {
        int c = tid >> 3, s = tid & 7;
        float mx = -INFINITY, sm = 0.f;
        const float* fb = feats + (size_t)b * NN * PP;
        for (int m = s; m < nsel; m += 8) {
            float wf = wsel[m] * fb[(size_t)isel[m] * PP + c];
            mx = fmaxf(mx, wf);
            sm += wf;
        }
        redmax[c * 8 + s] = mx;
        redsum[c * 8 + s] = sm;
    }
    if (tid < FF) urow[tid] = x[((size_t)b * NN + i) * FF + tid];
    __syncthreads();
    if (tid < PP) {
        float mx = -INFINITY, sm = 0.f;
        #pragma unroll
        for (int s = 0; s < 8; s++) { mx = fmaxf(mx, redmax[tid * 8 + s]); sm += redsum[tid * 8 + s]; }
        urow[FF + tid] = mx;
        urow[FF + PP + tid] = sm / (float)(K - 1);
    }
    __syncthreads();

    // ---- out = tanh(urow @ Wo + bo) : 42 threads, coalesced Wo reads ----
    if (tid < OO) {
        float acc = bo[tid];
        #pragma unroll 4
        for (int k = 0; k < FPDIM; k++) acc = fmaf(urow[k], Wo[k * OO + tid], acc);
        out[((size_t)b * NN + i) * OO + tid] = tanhf(acc);
    }
}

extern "C" void kernel_launch(void* const* d_in, const int* in_sizes, int n_in,
                              void* d_out, int out_size, void* d_ws, size_t ws_size,
                              hipStream_t stream) {
    const float* x  = (const float*)d_in[0];
    const float* Ws = (const float*)d_in[1];
    const float* bs = (const float*)d_in[2];
    const float* Wf = (const float*)d_in[3];
    const float* bf = (const float*)d_in[4];
    const float* Wo = (const float*)d_in[5];
    const float* bo = (const float*)d_in[6];
    const int*   nn = (const int*)d_in[7];
    float* out = (float*)d_out;

    float* coords = (float*)d_ws;                          // B*N*4 floats = 512 KB
    float* feats  = coords + (size_t)BB * NN * SS;         // B*N*22 floats = 2.75 MB

    precompute_kernel<<<(BB * NN) / 256, 256, 0, stream>>>(x, Ws, bs, Wf, bf, coords, feats);
    gravnet_kernel<<<BB * NN, 256, 0, stream>>>(x, coords, feats, Wo, bo, nn, out);
}

// Round 2
// 299.472 us; speedup vs baseline: 1.1907x; 1.1907x over previous
//
#include <hip/hip_runtime.h>
#include <math.h>

#define BB 16
#define NN 2048
#define FF 64
#define SS 4
#define PP 22
#define OO 42
#define FPDIM (FF + 2*PP)   // 108
#define NBIN 2048
#define NBINP (NBIN + 64)   // padded: bin k stored at k + (k>>5)

// ---------------- Kernel 1: coords = x@W_s + b_s ; feats = x@W_f + b_f ----------------
__global__ __launch_bounds__(256) void precompute_kernel(
    const float* __restrict__ x, const float* __restrict__ Ws, const float* __restrict__ bs,
    const float* __restrict__ Wf, const float* __restrict__ bf,
    float* __restrict__ coords, float* __restrict__ feats)
{
    int row = blockIdx.x * 256 + threadIdx.x;   // 0 .. B*N-1
    if (row >= BB * NN) return;

    const float4* x4 = (const float4*)(x + (size_t)row * FF);
    float c0 = bs[0], c1 = bs[1], c2 = bs[2], c3 = bs[3];
    float f[PP];
    #pragma unroll
    for (int c = 0; c < PP; c++) f[c] = bf[c];

    #pragma unroll
    for (int k4 = 0; k4 < FF / 4; k4++) {
        float4 xv = x4[k4];
        float xs[4] = {xv.x, xv.y, xv.z, xv.w};
        #pragma unroll
        for (int r = 0; r < 4; r++) {
            int k = k4 * 4 + r;
            float xk = xs[r];
            c0 = fmaf(xk, Ws[k * SS + 0], c0);
            c1 = fmaf(xk, Ws[k * SS + 1], c1);
            c2 = fmaf(xk, Ws[k * SS + 2], c2);
            c3 = fmaf(xk, Ws[k * SS + 3], c3);
            #pragma unroll
            for (int c = 0; c < PP; c++) f[c] = fmaf(xk, Wf[k * PP + c], f[c]);
        }
    }
    float4* cp = (float4*)(coords + (size_t)row * SS);
    *cp = make_float4(c0, c1, c2, c3);
    float* fo = feats + (size_t)row * PP;
    #pragma unroll
    for (int c = 0; c < PP; c++) fo[c] = f[c];
}

// ---------------- Kernel 2: block per query ----------------
__global__ __launch_bounds__(256) void gravnet_kernel(
    const float* __restrict__ x, const float* __restrict__ coords, const float* __restrict__ feats,
    const float* __restrict__ Wo, const float* __restrict__ bo,
    const int* __restrict__ nnbr, float* __restrict__ out)
{
    const int tid = threadIdx.x;
    const int bid = blockIdx.x;
    const int b = bid >> 11;       // / 2048
    const int i = bid & (NN - 1);

    int K = *nnbr;                 // 40 expected
    if (K < 2) K = 2;
    if (K > 64) K = 64;

    __shared__ float d2s[NN];                 // 8 KB
    __shared__ unsigned int hist[NBINP];      // 8.25 KB, padded for conflict-free scan
    __shared__ int sh_T, sh_rank, sh_count;
    __shared__ int selcount, eqcount;
    __shared__ int   isel[64];
    __shared__ float wsel[64];
    __shared__ int      eq_j[64];
    __shared__ unsigned eq_v[64];
    __shared__ float redmax[PP * 8];
    __shared__ float redsum[PP * 8];
    __shared__ float urow[FPDIM];

    const float4* cb = (const float4*)(coords + (size_t)b * NN * SS);
    float4 q = cb[i];              // block-uniform

    // ---- zero hist + control ----
    #pragma unroll
    for (int r = 0; r < 9; r++) {
        int idx = r * 256 + tid;
        if (idx < NBINP) hist[idx] = 0;
    }
    if (tid == 0) { selcount = 0; eqcount = 0; }
    __syncthreads();

    // ---- distances + store + fused level-0 histogram (bits [31:21]) ----
    #pragma unroll
    for (int r = 0; r < NN / 256; r++) {
        int j = r * 256 + tid;
        float4 cj = cb[j];
        float d0 = q.x - cj.x, d1 = q.y - cj.y, d2v = q.z - cj.z, d3 = q.w - cj.w;
        float d2 = d0 * d0 + d1 * d1 + d2v * d2v + d3 * d3;
        d2s[j] = d2;
        unsigned bin = __float_as_uint(d2) >> 21;           // <= 0x7FF (sign bit 0)
        atomicAdd(&hist[bin + (bin >> 5)], 1u);
    }
    __syncthreads();

    // ---- exact select: 11/11/10-bit radix digits, early-exit when bin count <= 64 ----
    unsigned prefix = 0;
    int shift = 21;
    int rank = K;
    int c = 0;
    int level = 0;
    while (true) {
        // scan hist with wave 0 (padded layout -> conflict-free)
        if (tid < 64) {
            const unsigned base = (unsigned)tid * 33u;      // bin tid*32 at addr tid*33
            int sum = 0;
            #pragma unroll
            for (int s = 0; s < 32; s++) sum += (int)hist[base + s];
            int inc = sum;
            #pragma unroll
            for (int off = 1; off < 64; off <<= 1) {
                int t = __shfl_up(inc, off, 64);
                if (tid >= off) inc += t;
            }
            int excl = inc - sum;
            if (excl < rank && rank <= inc) {               // exactly one lane
                int acc = excl;
                #pragma unroll 4
                for (int s = 0; s < 32; s++) {
                    int h = (int)hist[base + s];
                    if (acc + h >= rank) {
                        sh_T = tid * 32 + s;
                        sh_count = h;
                        sh_rank = rank - acc;
                        break;
                    }
                    acc += h;
                }
            }
        }
        __syncthreads();
        int nb = (level == 2) ? 10 : 11;
        prefix = (prefix << nb) | (unsigned)sh_T;
        rank = sh_rank;
        c = sh_count;
        if (c <= 64 || shift == 0) break;

        // ---- rare refinement level ----
        level++;
        nb = (level == 2) ? 10 : 11;
        shift -= nb;
        #pragma unroll
        for (int r = 0; r < 9; r++) {
            int idx = r * 256 + tid;
            if (idx < NBINP) hist[idx] = 0;
        }
        __syncthreads();
        const unsigned hib = (unsigned)(shift + nb);
        const unsigned msk = (1u << nb) - 1u;
        #pragma unroll
        for (int r = 0; r < NN / 256; r++) {
            int j = r * 256 + tid;
            unsigned v = __float_as_uint(d2s[j]);
            if ((v >> hib) == prefix) {
                unsigned d = (v >> shift) & msk;
                atomicAdd(&hist[d + (d >> 5)], 1u);
            }
        }
        __syncthreads();
    }
    const unsigned lo = prefix << shift;   // all v < lo are in top-K; bin [lo, lo+2^shift) partial

    // ---- collect: below-bin always selected (minus self); in-bin -> candidate list ----
    #pragma unroll
    for (int r = 0; r < NN / 256; r++) {
        int j = r * 256 + tid;
        float d2 = d2s[j];
        unsigned v = __float_as_uint(d2);
        if (v < lo) {
            if (j != i) {
                int m = atomicAdd(&selcount, 1);
                if (m < 64) { isel[m] = j; wsel[m] = expf(-d2); }
            }
        } else if ((v >> shift) == prefix) {
            int e = atomicAdd(&eqcount, 1);
            if (e < 64) { eq_j[e] = j; eq_v[e] = v; }
        }
    }
    __syncthreads();

    // ---- tie-break: wave-parallel rank of (value, index) keys, take `rank` smallest ----
    if (tid < 64) {
        int e = eqcount; if (e > 64) e = 64;
        unsigned long long mykey = 0xFFFFFFFFFFFFFFFFull;
        if (tid < e) mykey = ((unsigned long long)eq_v[tid] << 32) | (unsigned)eq_j[tid];
        int myrank = 0;
        for (int u = 0; u < e; u++) {   // broadcast reads, conflict-free
            unsigned long long k = ((unsigned long long)eq_v[u] << 32) | (unsigned)eq_j[u];
            myrank += (k < mykey) ? 1 : 0;
        }
        if (tid < e && myrank < rank && eq_j[tid] != i) {
            int m = atomicAdd(&selcount, 1);
            if (m < 64) { isel[m] = eq_j[tid]; wsel[m] = expf(-__uint_as_float(eq_v[tid])); }
        }
    }
    __syncthreads();
    int nsel = selcount; if (nsel > 64) nsel = 64;    // expect K-1 = 39

    // ---- weighted max / mean over neighbors, 8 partials per channel ----
    if (tid < PP * 8) {
        int cc = tid >> 3, s = tid & 7;
        float mx = -INFINITY, sm = 0.f;
        const float* fb = feats + (size_t)b * NN * PP;
        for (int m = s; m < nsel; m += 8) {
            float wf = wsel[m] * fb[(size_t)isel[m] * PP + cc];
            mx = fmaxf(mx, wf);
            sm += wf;
        }
        redmax[cc * 8 + s] = mx;
        redsum[cc * 8 + s] = sm;
    }
    if (tid < FF) urow[tid] = x[((size_t)b * NN + i) * FF + tid];
    __syncthreads();
    if (tid < PP) {
        float mx = -INFINITY, sm = 0.f;
        #pragma unroll
        for (int s = 0; s < 8; s++) { mx = fmaxf(mx, redmax[tid * 8 + s]); sm += redsum[tid * 8 + s]; }
        urow[FF + tid] = mx;
        urow[FF + PP + tid] = sm / (float)(K - 1);
    }
    __syncthreads();

    // ---- out = tanh(urow @ Wo + bo) ----
    if (tid < OO) {
        float acc = bo[tid];
        #pragma unroll 4
        for (int k = 0; k < FPDIM; k++) acc = fmaf(urow[k], Wo[k * OO + tid], acc);
        out[((size_t)b * NN + i) * OO + tid] = tanhf(acc);
    }
}

extern "C" void kernel_launch(void* const* d_in, const int* in_sizes, int n_in,
                              void* d_out, int out_size, void* d_ws, size_t ws_size,
                              hipStream_t stream) {
    const float* x  = (const float*)d_in[0];
    const float* Ws = (const float*)d_in[1];
    const float* bs = (const float*)d_in[2];
    const float* Wf = (const float*)d_in[3];
    const float* bf = (const float*)d_in[4];
    const float* Wo = (const float*)d_in[5];
    const float* bo = (const float*)d_in[6];
    const int*   nn = (const int*)d_in[7];
    float* out = (float*)d_out;

    float* coords = (float*)d_ws;                          // B*N*4 floats
    float* feats  = coords + (size_t)BB * NN * SS;         // B*N*22 floats

    precompute_kernel<<<(BB * NN) / 256, 256, 0, stream>>>(x, Ws, bs, Wf, bf, coords, feats);
    gravnet_kernel<<<BB * NN, 256, 0, stream>>>(x, coords, feats, Wo, bo, nn, out);
}

// Round 3
// 258.869 us; speedup vs baseline: 1.3774x; 1.1569x over previous
//
#include <hip/hip_runtime.h>
#include <math.h>

#define BB 16
#define NN 2048
#define FF 64
#define SS 4
#define PP 22
#define OO 42
#define FPDIM (FF + 2*PP)   // 108

// ---------------- Kernel 1: coords = x@W_s + b_s ; feats = x@W_f + b_f ----------------
__global__ __launch_bounds__(256) void precompute_kernel(
    const float* __restrict__ x, const float* __restrict__ Ws, const float* __restrict__ bs,
    const float* __restrict__ Wf, const float* __restrict__ bf,
    float* __restrict__ coords, float* __restrict__ feats)
{
    int row = blockIdx.x * 256 + threadIdx.x;   // 0 .. B*N-1
    if (row >= BB * NN) return;

    const float4* x4 = (const float4*)(x + (size_t)row * FF);
    float c0 = bs[0], c1 = bs[1], c2 = bs[2], c3 = bs[3];
    float f[PP];
    #pragma unroll
    for (int c = 0; c < PP; c++) f[c] = bf[c];

    #pragma unroll
    for (int k4 = 0; k4 < FF / 4; k4++) {
        float4 xv = x4[k4];
        float xs[4] = {xv.x, xv.y, xv.z, xv.w};
        #pragma unroll
        for (int r = 0; r < 4; r++) {
            int k = k4 * 4 + r;
            float xk = xs[r];
            c0 = fmaf(xk, Ws[k * SS + 0], c0);
            c1 = fmaf(xk, Ws[k * SS + 1], c1);
            c2 = fmaf(xk, Ws[k * SS + 2], c2);
            c3 = fmaf(xk, Ws[k * SS + 3], c3);
            #pragma unroll
            for (int c = 0; c < PP; c++) f[c] = fmaf(xk, Wf[k * PP + c], f[c]);
        }
    }
    float4* cp = (float4*)(coords + (size_t)row * SS);
    *cp = make_float4(c0, c1, c2, c3);
    float* fo = feats + (size_t)row * PP;
    #pragma unroll
    for (int c = 0; c < PP; c++) fo[c] = f[c];
}

// ---------------- Kernel 2: wave-per-query kNN select + weighted max/mean aggregation ----------------
// No __syncthreads: each wave uses its private LDS region; wave_barrier() stops compiler reordering.
__global__ __launch_bounds__(256) void knn_agg_kernel(
    const float* __restrict__ coords, const float* __restrict__ feats,
    const int* __restrict__ nnbr, float* __restrict__ agg)
{
    const int lane = threadIdx.x & 63;
    const int w    = threadIdx.x >> 6;
    const int q    = blockIdx.x * 4 + w;       // 0..32767
    const int b    = q >> 11;
    const int i    = q & (NN - 1);

    int K = *nnbr; K = K < 2 ? 2 : (K > 64 ? 64 : K);

    __shared__ __align__(16) unsigned hist[4][512];   // per-wave 512-bin histogram
    __shared__ int   selc[4], eqc[4];
    __shared__ int   isel[4][64];
    __shared__ float wsel[4][64];
    __shared__ unsigned candv[4][64];
    __shared__ int   candj[4][64];

    // zero hist (strided, conflict-free) + counters
    #pragma unroll
    for (int s = 0; s < 8; s++) hist[w][s * 64 + lane] = 0u;
    if (lane == 0) { selc[w] = 0; eqc[w] = 0; }
    __builtin_amdgcn_wave_barrier();

    const float4* cb = (const float4*)(coords + (size_t)b * NN * SS);
    float4 qc = cb[i];

    // ---- distances: all 2048 kept in 32 VGPRs/lane; fused quarter-octave histogram ----
    float d2r[32];
    #pragma unroll
    for (int r = 0; r < 32; r++) {
        int j = r * 64 + lane;
        float4 c = cb[j];
        float d0 = qc.x - c.x, d1 = qc.y - c.y, d2 = qc.z - c.z, d3 = qc.w - c.w;
        float v = d0 * d0 + d1 * d1 + d2 * d2 + d3 * d3;
        d2r[r] = v;
        int t = (int)(__float_as_uint(v) >> 22) - 180;
        t = t < 0 ? 0 : (t > 511 ? 511 : t);
        atomicAdd(&hist[w][t], 1u);
        if ((r & 7) == 7) __builtin_amdgcn_wave_barrier();  // cap load in-flight -> VGPR pressure
    }
    __builtin_amdgcn_wave_barrier();

    // ---- scan 512 bins: find bin of the K-th smallest ----
    int T, rank, count;
    {
        uint4 h0 = *((const uint4*)&hist[w][lane * 8]);
        uint4 h1 = *((const uint4*)&hist[w][lane * 8 + 4]);
        unsigned c8[8] = {h0.x, h0.y, h0.z, h0.w, h1.x, h1.y, h1.z, h1.w};
        int sum = 0;
        #pragma unroll
        for (int s = 0; s < 8; s++) sum += (int)c8[s];
        int inc = sum;
        #pragma unroll
        for (int off = 1; off < 64; off <<= 1) {
            int t2 = __shfl_up(inc, off, 64);
            if (lane >= off) inc += t2;
        }
        int excl = inc - sum;
        bool found = (excl < K) && (K <= inc);
        int myT = 0, myR = 0, myC = 0;
        int acc2 = excl; bool done = false;
        #pragma unroll
        for (int s = 0; s < 8; s++) {
            int h = (int)c8[s];
            if (!done) {
                if (acc2 + h >= K) { myT = lane * 8 + s; myR = K - acc2; myC = h; done = true; }
                else acc2 += h;
            }
        }
        unsigned long long m = __ballot(found);
        int src = __ffsll((long long)m) - 1;
        T     = __shfl(myT, src, 64);
        rank  = __shfl(myR, src, 64);
        count = __shfl(myC, src, 64);
    }

    // ---- window of the target bin ----
    unsigned winLo, winHi;
    if (T == 0)        { winLo = 0u;          winHi = 181u << 22; }
    else if (T == 511) { winLo = 691u << 22;  winHi = 0xFFFFFFFFu; }
    else               { winLo = (unsigned)(T + 180) << 22; winHi = winLo + (1u << 22); }

    // ---- exact refinement (rare): equality-prefix radix, or full restart for clamped bins ----
    if (count > 64) {
        unsigned pref; int prefShift;
        if (T == 0 || T == 511) { pref = 0u; prefShift = 31; rank = K; count = NN; }
        else                    { pref = (unsigned)(T + 180); prefShift = 22; }
        while (count > 64 && prefShift > 0) {
            int nb = prefShift < 8 ? prefShift : 8;
            int ns = prefShift - nb;
            int bins = 1 << nb;
            #pragma unroll
            for (int s = 0; s < 4; s++) hist[w][s * 64 + lane] = 0u;
            __builtin_amdgcn_wave_barrier();
            #pragma unroll
            for (int r = 0; r < 32; r++) {
                unsigned v = __float_as_uint(d2r[r]);
                if ((v >> prefShift) == pref)
                    atomicAdd(&hist[w][(v >> ns) & (unsigned)(bins - 1)], 1u);
            }
            __builtin_amdgcn_wave_barrier();
            uint4 hh = make_uint4(0u, 0u, 0u, 0u);
            if (lane * 4 < bins) hh = *((const uint4*)&hist[w][lane * 4]);
            unsigned c4[4] = {hh.x, hh.y, hh.z, hh.w};
            int sum = 0;
            #pragma unroll
            for (int s = 0; s < 4; s++) sum += (int)c4[s];
            int inc = sum;
            #pragma unroll
            for (int off = 1; off < 64; off <<= 1) {
                int t2 = __shfl_up(inc, off, 64);
                if (lane >= off) inc += t2;
            }
            int excl = inc - sum;
            bool found = (excl < rank) && (rank <= inc);
            int myT = 0, myR = 0, myC = 0;
            int acc2 = excl; bool done = false;
            #pragma unroll
            for (int s = 0; s < 4; s++) {
                int h = (int)c4[s];
                if (!done) {
                    if (acc2 + h >= rank) { myT = lane * 4 + s; myR = rank - acc2; myC = h; done = true; }
                    else acc2 += h;
                }
            }
            unsigned long long m = __ballot(found);
            int src = __ffsll((long long)m) - 1;
            int T2 = __shfl(myT, src, 64);
            rank   = __shfl(myR, src, 64);
            count  = __shfl(myC, src, 64);
            pref = (pref << nb) | (unsigned)T2;
            prefShift = ns;
        }
        winLo = pref << prefShift;
        winHi = winLo + (1u << prefShift);
    }

    // ---- collect: below-window -> selected (skip self); in-window -> candidates ----
    __builtin_amdgcn_wave_barrier();
    #pragma unroll
    for (int r = 0; r < 32; r++) {
        unsigned v = __float_as_uint(d2r[r]);
        int j = r * 64 + lane;
        if (v < winLo) {
            if (j != i) {
                int m = atomicAdd(&selc[w], 1);
                if (m < 64) { isel[w][m] = j; wsel[w][m] = d2r[r]; }  // store d2; exp later
            }
        } else if (v < winHi) {
            int e = atomicAdd(&eqc[w], 1);
            if (e < 64) { candv[w][e] = v; candj[w][e] = j; }
        }
    }
    __builtin_amdgcn_wave_barrier();

    // ---- tie-break: take `rank` smallest (value, index) among candidates ----
    {
        int e = eqc[w]; e = e > 64 ? 64 : e;
        unsigned long long mykey = ~0ull;
        int mj = 0; unsigned mv = 0u;
        if (lane < e) {
            mv = candv[w][lane]; mj = candj[w][lane];
            mykey = ((unsigned long long)mv << 32) | (unsigned)mj;
        }
        int mr = 0;
        for (int u = 0; u < e; u++) {
            unsigned long long k2 = ((unsigned long long)candv[w][u] << 32) | (unsigned)candj[w][u];
            mr += (k2 < mykey) ? 1 : 0;
        }
        if (lane < e && mr < rank && mj != i) {
            int m = atomicAdd(&selc[w], 1);
            if (m < 64) { isel[w][m] = mj; wsel[w][m] = __uint_as_float(mv); }
        }
    }
    __builtin_amdgcn_wave_barrier();

    int nsel = selc[w]; nsel = nsel > 64 ? 64 : nsel;   // expect K-1 = 39
    if (lane < nsel) wsel[w][lane] = __expf(-wsel[w][lane]);
    __builtin_amdgcn_wave_barrier();

    // ---- weighted max / mean: lanes 0-21 do even m, lanes 32-53 odd m ----
    const float* fb = feats + (size_t)b * NN * PP;
    int g = lane >> 5, c = lane & 31;
    float mx = -INFINITY, sm = 0.f;
    if (c < PP) {
        for (int m = g; m < nsel; m += 2) {
            int j = isel[w][m]; float wt = wsel[w][m];
            float f = fb[(size_t)j * PP + c];
            float wf = wt * f;
            mx = fmaxf(mx, wf); sm += wf;
        }
    }
    float mx2 = __shfl_xor(mx, 32, 64);
    float sm2 = __shfl_xor(sm, 32, 64);
    mx = fmaxf(mx, mx2); sm += sm2;
    if (g == 0 && c < PP) {
        agg[(size_t)q * 44 + c]      = mx;
        agg[(size_t)q * 44 + PP + c] = sm / (float)(K - 1);
    }
}

// ---------------- Kernel 3: out = tanh([x | agg] @ Wo + bo) ----------------
__global__ __launch_bounds__(128) void out_kernel(
    const float* __restrict__ x, const float* __restrict__ agg,
    const float* __restrict__ Wo, const float* __restrict__ bo,
    float* __restrict__ out)
{
    __shared__ float sX[128 * 65];                   // stride 65: conflict-free column reads
    __shared__ float sA[128 * 45];                   // stride 45: gcd(45,32)=1
    __shared__ __align__(16) float sWo[FPDIM * 44];  // rows padded to 44 for float4 reads
    __shared__ float sbo[OO];

    const int t = threadIdx.x;
    const int rowBase = blockIdx.x * 128;

    // stage x rows (coalesced global, scalar LDS writes to padded layout)
    {
        const float4* xg = (const float4*)(x + (size_t)rowBase * FF);
        #pragma unroll
        for (int it = 0; it < 16; it++) {            // 128*64/4 = 2048 float4
            int idx = it * 128 + t;
            float4 v = xg[idx];
            int row = idx >> 4, col = (idx & 15) << 2;
            float* p = &sX[row * 65 + col];
            p[0] = v.x; p[1] = v.y; p[2] = v.z; p[3] = v.w;
        }
        for (int it = 0; it < 44; it++) {            // 128*44 floats
            int idx = it * 128 + t;
            int row = idx / 44, col = idx - row * 44;
            sA[row * 45 + col] = agg[(size_t)rowBase * 44 + idx];
        }
        for (int it = 0; it < 36; it++) {            // 108*42 = 4536 floats
            int idx = it * 128 + t;
            if (idx < FPDIM * OO) {
                int row = idx / OO, col = idx - row * OO;
                sWo[row * 44 + col] = Wo[idx];
            }
        }
        if (t < OO) sbo[t] = bo[t];
    }
    __syncthreads();

    float acc[44];
    #pragma unroll
    for (int o = 0; o < 44; o++) acc[o] = (o < OO) ? sbo[o] : 0.f;

    const float* xr = &sX[t * 65];
    const float* ar = &sA[t * 45];
    for (int k = 0; k < FF; k++) {
        float u = xr[k];
        const float* wrow = &sWo[k * 44];
        #pragma unroll
        for (int o4 = 0; o4 < 11; o4++) {
            float4 wv = *((const float4*)&wrow[o4 * 4]);
            acc[o4*4+0] = fmaf(u, wv.x, acc[o4*4+0]);
            acc[o4*4+1] = fmaf(u, wv.y, acc[o4*4+1]);
            acc[o4*4+2] = fmaf(u, wv.z, acc[o4*4+2]);
            acc[o4*4+3] = fmaf(u, wv.w, acc[o4*4+3]);
        }
    }
    for (int k = 0; k < 2 * PP; k++) {
        float u = ar[k];
        const float* wrow = &sWo[(FF + k) * 44];
        #pragma unroll
        for (int o4 = 0; o4 < 11; o4++) {
            float4 wv = *((const float4*)&wrow[o4 * 4]);
            acc[o4*4+0] = fmaf(u, wv.x, acc[o4*4+0]);
            acc[o4*4+1] = fmaf(u, wv.y, acc[o4*4+1]);
            acc[o4*4+2] = fmaf(u, wv.z, acc[o4*4+2]);
            acc[o4*4+3] = fmaf(u, wv.w, acc[o4*4+3]);
        }
    }

    __syncthreads();                                  // done reading sA as input
    float* orow = &sA[t * 43];                        // reuse sA (stride 43, gcd(43,32)=1)
    #pragma unroll
    for (int o = 0; o < OO; o++) {
        float a = acc[o];
        a = a < -12.f ? -12.f : (a > 12.f ? 12.f : a);
        float e2 = __expf(2.f * a);
        orow[o] = (e2 - 1.f) / (e2 + 1.f);
    }
    __syncthreads();
    for (int it = 0; it < 42; it++) {                 // coalesced store of 128*42 floats
        int idx = it * 128 + t;
        int row = idx / 42, col = idx - row * 42;
        out[(size_t)rowBase * 42 + idx] = sA[row * 43 + col];
    }
}

extern "C" void kernel_launch(void* const* d_in, const int* in_sizes, int n_in,
                              void* d_out, int out_size, void* d_ws, size_t ws_size,
                              hipStream_t stream) {
    const float* x  = (const float*)d_in[0];
    const float* Ws = (const float*)d_in[1];
    const float* bs = (const float*)d_in[2];
    const float* Wf = (const float*)d_in[3];
    const float* bf = (const float*)d_in[4];
    const float* Wo = (const float*)d_in[5];
    const float* bo = (const float*)d_in[6];
    const int*   nn = (const int*)d_in[7];
    float* out = (float*)d_out;

    float* coords = (float*)d_ws;                              // 16*2048*4  = 512 KB
    float* feats  = coords + (size_t)BB * NN * SS;             // 16*2048*22 = 2.75 MB
    float* agg    = feats  + (size_t)BB * NN * PP;             // 32768*44   = 5.5 MB

    precompute_kernel<<<(BB * NN) / 256, 256, 0, stream>>>(x, Ws, bs, Wf, bf, coords, feats);
    knn_agg_kernel<<<(BB * NN) / 4, 256, 0, stream>>>(coords, feats, nn, agg);
    out_kernel<<<(BB * NN) / 128, 128, 0, stream>>>(x, agg, Wo, bo, out);
}

// Round 4
// 240.678 us; speedup vs baseline: 1.4815x; 1.0756x over previous
//
#include <hip/hip_runtime.h>
#include <math.h>

#define BB 16
#define NN 2048
#define FF 64
#define SS 4
#define PP 22
#define OO 42
#define FPDIM (FF + 2*PP)   // 108

// ---------------- Kernel 1: coords = x@W_s + b_s ; feats = x@W_f + b_f ----------------
__global__ __launch_bounds__(256) void precompute_kernel(
    const float* __restrict__ x, const float* __restrict__ Ws, const float* __restrict__ bs,
    const float* __restrict__ Wf, const float* __restrict__ bf,
    float* __restrict__ coords, float* __restrict__ feats)
{
    int row = blockIdx.x * 256 + threadIdx.x;   // 0 .. B*N-1
    if (row >= BB * NN) return;

    const float4* x4 = (const float4*)(x + (size_t)row * FF);
    float c0 = bs[0], c1 = bs[1], c2 = bs[2], c3 = bs[3];
    float f[PP];
    #pragma unroll
    for (int c = 0; c < PP; c++) f[c] = bf[c];

    #pragma unroll
    for (int k4 = 0; k4 < FF / 4; k4++) {
        float4 xv = x4[k4];
        float xs[4] = {xv.x, xv.y, xv.z, xv.w};
        #pragma unroll
        for (int r = 0; r < 4; r++) {
            int k = k4 * 4 + r;
            float xk = xs[r];
            c0 = fmaf(xk, Ws[k * SS + 0], c0);
            c1 = fmaf(xk, Ws[k * SS + 1], c1);
            c2 = fmaf(xk, Ws[k * SS + 2], c2);
            c3 = fmaf(xk, Ws[k * SS + 3], c3);
            #pragma unroll
            for (int c = 0; c < PP; c++) f[c] = fmaf(xk, Wf[k * PP + c], f[c]);
        }
    }
    float4* cp = (float4*)(coords + (size_t)row * SS);
    *cp = make_float4(c0, c1, c2, c3);
    float* fo = feats + (size_t)row * PP;
    #pragma unroll
    for (int c = 0; c < PP; c++) fo[c] = f[c];
}

// ---------------- Kernel 2: wave-per-query kNN via register counting bisection ----------------
// No histogram, no LDS in the select loop: all 2048 d2 live in 32 VGPRs/lane;
// threshold found by counting passes (cmp+addc), seeded by mean-of-lane-minima.
__global__ __launch_bounds__(128) void knn_agg_kernel(
    const float* __restrict__ coords, const float* __restrict__ feats,
    const int* __restrict__ nnbr, float* __restrict__ agg)
{
    const int lane = threadIdx.x & 63;
    const int w    = threadIdx.x >> 6;
    const int q    = blockIdx.x * 2 + w;       // 0..32767
    const int b    = q >> 11;
    const int i    = q & (NN - 1);

    int K = *nnbr; K = K < 2 ? 2 : (K > 64 ? 64 : K);

    __shared__ int   selc[2], eqc[2];
    __shared__ int   isel[2][64];
    __shared__ float wsel[2][64];
    __shared__ unsigned candv[2][64];
    __shared__ int   candj[2][64];

    if (lane == 0) { selc[w] = 0; eqc[w] = 0; }

    const float4* cb = (const float4*)(coords + (size_t)b * NN * SS);
    float4 qc = cb[i];

    // ---- distances: all 2048 kept in 32 VGPRs/lane; track per-lane min ----
    float d2r[32];
    float lmin = INFINITY;
    #pragma unroll
    for (int r = 0; r < 32; r++) {
        int j = r * 64 + lane;
        float4 c = cb[j];
        float d0 = qc.x - c.x, d1 = qc.y - c.y, d2 = qc.z - c.z, d3 = qc.w - c.w;
        float v = d0 * d0 + d1 * d1 + d2 * d2 + d3 * d3;
        d2r[r] = v;
        lmin = fminf(lmin, v);
    }

    // ---- first-probe estimator: mean of per-lane minima ~ K/N quantile ----
    float s = lmin;
    #pragma unroll
    for (int off = 1; off < 64; off <<= 1) s += __shfl_xor(s, off, 64);
    float t0 = s * (1.0f / 64.0f);

    // ---- bisection on the threshold: invariant cnt_lt(lo) < K <= cnt_lt(hi) ----
    unsigned loU = 0u, hiU = 0x7F800000u;   // [0, +inf)
    int cLo = 0, cHi = NN;
    float tPrev = t0; int cPrev = -1;
    int probes = 0;
    while (cHi - cLo > 64 && hiU - loU > 1u && probes < 34) {
        unsigned tU;
        if (probes == 0 && t0 > 0.f) {
            tU = __float_as_uint(t0);
        } else if (cPrev > 0 && probes < 8) {
            // local power law F(x) ~ x^2  ->  aim t' = t * sqrt(K/c)
            float g = tPrev * __fsqrt_rn((float)K / (float)cPrev);
            tU = __float_as_uint(g);
        } else if (cPrev == 0 && probes < 8) {
            tU = __float_as_uint(tPrev * 4.0f);
        } else {
            tU = loU + ((hiU - loU) >> 1);
        }
        if (tU <= loU || tU >= hiU) tU = loU + ((hiU - loU) >> 1);   // guaranteed shrink
        float t = __uint_as_float(tU);
        int c = 0;
        #pragma unroll
        for (int r = 0; r < 32; r++) c += (d2r[r] < t) ? 1 : 0;
        #pragma unroll
        for (int off = 1; off < 64; off <<= 1) c += __shfl_xor(c, off, 64);
        if (c >= K) { hiU = tU; cHi = c; } else { loU = tU; cLo = c; }
        tPrev = t; cPrev = c;
        probes++;
    }

    const float lo = __uint_as_float(loU);
    const float hi = __uint_as_float(hiU);
    const int  need = K - cLo;              // in [1, K]; window holds >= need values

    // ---- collect: v < lo -> selected (skip self); v in [lo, hi) -> candidates ----
    __builtin_amdgcn_wave_barrier();
    #pragma unroll
    for (int r = 0; r < 32; r++) {
        float v = d2r[r];
        int j = r * 64 + lane;
        if (v < lo) {
            if (j != i) {
                int m = atomicAdd(&selc[w], 1);
                if (m < 64) { isel[w][m] = j; wsel[w][m] = v; }   // store d2; exp later
            }
        } else if (v < hi) {
            int e = atomicAdd(&eqc[w], 1);
            if (e < 64) { candv[w][e] = __float_as_uint(v); candj[w][e] = j; }
        }
    }
    __builtin_amdgcn_wave_barrier();

    // ---- rank candidates by (value, index); append `need` smallest, skipping self ----
    {
        int e = eqc[w]; e = e > 64 ? 64 : e;
        unsigned long long mykey = ~0ull;
        int mj = 0; unsigned mv = 0u;
        if (lane < e) {
            mv = candv[w][lane]; mj = candj[w][lane];
            mykey = ((unsigned long long)mv << 32) | (unsigned)mj;
        }
        int mr = 0;
        for (int u = 0; u < e; u++) {        // LDS broadcast reads, conflict-free
            unsigned long long k2 = ((unsigned long long)candv[w][u] << 32) | (unsigned)candj[w][u];
            mr += (k2 < mykey) ? 1 : 0;
        }
        if (lane < e && mr < need && mj != i) {
            int m = atomicAdd(&selc[w], 1);
            if (m < 64) { isel[w][m] = mj; wsel[w][m] = __uint_as_float(mv); }
        }
    }
    __builtin_amdgcn_wave_barrier();

    int nsel = selc[w]; nsel = nsel > 64 ? 64 : nsel;   // expect K-1 = 39
    if (lane < nsel) wsel[w][lane] = __expf(-wsel[w][lane]);
    __builtin_amdgcn_wave_barrier();

    // ---- weighted max / mean: lanes 0-21 do even m, lanes 32-53 odd m ----
    const float* fb = feats + (size_t)b * NN * PP;
    int g = lane >> 5, c = lane & 31;
    float mx = -INFINITY, sm = 0.f;
    if (c < PP) {
        for (int m = g; m < nsel; m += 2) {
            int j = isel[w][m]; float wt = wsel[w][m];
            float f = fb[(size_t)j * PP + c];
            float wf = wt * f;
            mx = fmaxf(mx, wf); sm += wf;
        }
    }
    float mx2 = __shfl_xor(mx, 32, 64);
    float sm2 = __shfl_xor(sm, 32, 64);
    mx = fmaxf(mx, mx2); sm += sm2;
    if (g == 0 && c < PP) {
        agg[(size_t)q * 44 + c]      = mx;
        agg[(size_t)q * 44 + PP + c] = sm / (float)(K - 1);
    }
}

// ---------------- Kernel 3: out = tanh([x | agg] @ Wo + bo) ----------------
__global__ __launch_bounds__(128) void out_kernel(
    const float* __restrict__ x, const float* __restrict__ agg,
    const float* __restrict__ Wo, const float* __restrict__ bo,
    float* __restrict__ out)
{
    __shared__ float sX[128 * 65];                   // stride 65: conflict-free column reads
    __shared__ float sA[128 * 45];                   // stride 45: gcd(45,32)=1
    __shared__ __align__(16) float sWo[FPDIM * 44];  // rows padded to 44 for float4 reads
    __shared__ float sbo[OO];

    const int t = threadIdx.x;
    const int rowBase = blockIdx.x * 128;

    {
        const float4* xg = (const float4*)(x + (size_t)rowBase * FF);
        #pragma unroll
        for (int it = 0; it < 16; it++) {            // 128*64/4 = 2048 float4
            int idx = it * 128 + t;
            float4 v = xg[idx];
            int row = idx >> 4, col = (idx & 15) << 2;
            float* p = &sX[row * 65 + col];
            p[0] = v.x; p[1] = v.y; p[2] = v.z; p[3] = v.w;
        }
        for (int it = 0; it < 44; it++) {            // 128*44 floats
            int idx = it * 128 + t;
            int row = idx / 44, col = idx - row * 44;
            sA[row * 45 + col] = agg[(size_t)rowBase * 44 + idx];
        }
        for (int it = 0; it < 36; it++) {            // 108*42 = 4536 floats
            int idx = it * 128 + t;
            if (idx < FPDIM * OO) {
                int row = idx / OO, col = idx - row * OO;
                sWo[row * 44 + col] = Wo[idx];
            }
        }
        if (t < OO) sbo[t] = bo[t];
    }
    __syncthreads();

    float acc[44];
    #pragma unroll
    for (int o = 0; o < 44; o++) acc[o] = (o < OO) ? sbo[o] : 0.f;

    const float* xr = &sX[t * 65];
    const float* ar = &sA[t * 45];
    for (int k = 0; k < FF; k++) {
        float u = xr[k];
        const float* wrow = &sWo[k * 44];
        #pragma unroll
        for (int o4 = 0; o4 < 11; o4++) {
            float4 wv = *((const float4*)&wrow[o4 * 4]);
            acc[o4*4+0] = fmaf(u, wv.x, acc[o4*4+0]);
            acc[o4*4+1] = fmaf(u, wv.y, acc[o4*4+1]);
            acc[o4*4+2] = fmaf(u, wv.z, acc[o4*4+2]);
            acc[o4*4+3] = fmaf(u, wv.w, acc[o4*4+3]);
        }
    }
    for (int k = 0; k < 2 * PP; k++) {
        float u = ar[k];
        const float* wrow = &sWo[(FF + k) * 44];
        #pragma unroll
        for (int o4 = 0; o4 < 11; o4++) {
            float4 wv = *((const float4*)&wrow[o4 * 4]);
            acc[o4*4+0] = fmaf(u, wv.x, acc[o4*4+0]);
            acc[o4*4+1] = fmaf(u, wv.y, acc[o4*4+1]);
            acc[o4*4+2] = fmaf(u, wv.z, acc[o4*4+2]);
            acc[o4*4+3] = fmaf(u, wv.w, acc[o4*4+3]);
        }
    }

    __syncthreads();                                  // done reading sA as input
    float* orow = &sA[t * 43];                        // reuse sA (stride 43, gcd(43,32)=1)
    #pragma unroll
    for (int o = 0; o < OO; o++) {
        float a = acc[o];
        a = a < -12.f ? -12.f : (a > 12.f ? 12.f : a);
        float e2 = __expf(2.f * a);
        orow[o] = (e2 - 1.f) / (e2 + 1.f);
    }
    __syncthreads();
    for (int it = 0; it < 42; it++) {                 // coalesced store of 128*42 floats
        int idx = it * 128 + t;
        int row = idx / 42, col = idx - row * 42;
        out[(size_t)rowBase * 42 + idx] = sA[row * 43 + col];
    }
}

extern "C" void kernel_launch(void* const* d_in, const int* in_sizes, int n_in,
                              void* d_out, int out_size, void* d_ws, size_t ws_size,
                              hipStream_t stream) {
    const float* x  = (const float*)d_in[0];
    const float* Ws = (const float*)d_in[1];
    const float* bs = (const float*)d_in[2];
    const float* Wf = (const float*)d_in[3];
    const float* bf = (const float*)d_in[4];
    const float* Wo = (const float*)d_in[5];
    const float* bo = (const float*)d_in[6];
    const int*   nn = (const int*)d_in[7];
    float* out = (float*)d_out;

    float* coords = (float*)d_ws;                              // 16*2048*4  = 512 KB
    float* feats  = coords + (size_t)BB * NN * SS;             // 16*2048*22 = 2.75 MB
    float* agg    = feats  + (size_t)BB * NN * PP;             // 32768*44   = 5.5 MB

    precompute_kernel<<<(BB * NN) / 256, 256, 0, stream>>>(x, Ws, bs, Wf, bf, coords, feats);
    knn_agg_kernel<<<(BB * NN) / 2, 128, 0, stream>>>(coords, feats, nn, agg);
    out_kernel<<<(BB * NN) / 128, 128, 0, stream>>>(x, agg, Wo, bo, out);
}